// Round 8
// baseline (271.327 us; speedup 1.0000x reference)
//
#include <hip/hip_runtime.h>
#include <hip/hip_cooperative_groups.h>

namespace cg = cooperative_groups;

#define GFINE 128
#define GC 64
#define NCELLS (GC * GC * GC)   // 262144
#define CIN 32
#define COUT 64
#define PREP_BLOCKS 512         // cooperative grid: 512 x 256 = 131072 threads

typedef __attribute__((ext_vector_type(8))) short bf16x8;   // 8 bf16 (4 VGPR)
typedef __attribute__((ext_vector_type(4))) float f32x4;    // MFMA acc

// round-to-nearest-even float -> bf16 bits
__device__ __forceinline__ short f2bf(float f) {
    union { float f; unsigned u; } v; v.f = f;
    unsigned r = v.u + 0x7fffu + ((v.u >> 16) & 1u);
    return (short)(r >> 16);
}

// workspace layout (tab needs no init — vacant slots masked by occ bits)
#define TAB_OFF   0u               // [NCELLS*8] int, 8 MB
#define OCC_OFF   8388608u         // [NCELLS] int, 1 MB, bit k = tap k occupied
#define CL_OFF    9437184u         // [<=NCELLS] int cellList: (occ8<<18)|cell
#define BS_OFF    10485760u        // [512] int block sums
#define WSWZ_OFF  10489856u        // 32 KB bf16 swizzled weights

// ---- Kernel 1 (cooperative): zero+wswz -> scatter -> sums -> scan -> compact ----
__global__ __launch_bounds__(256) void prep_kernel(
    const float* __restrict__ w, const int* __restrict__ pos, int n,
    char* __restrict__ ws, float* __restrict__ out_pos) {
    cg::grid_group grid = cg::this_grid();
    __shared__ int lds[256];
    const int tid = threadIdx.x, bid = blockIdx.x;
    const int gidx = bid * 256 + tid;            // 0..131071

    int* tab       = (int*)(ws + TAB_OFF);
    int* occ       = (int*)(ws + OCC_OFF);
    int* cellList  = (int*)(ws + CL_OFF);
    int* blockSums = (int*)(ws + BS_OFF);

    // Phase 0: zero occ (65536 int4) + swizzle weights (2048 bf16x8)
    if (gidx < NCELLS / 4)
        ((int4*)occ)[gidx] = make_int4(0, 0, 0, 0);
    if (gidx < 2048) {
        int lane = gidx & 63, cb = (gidx >> 6) & 3, k = gidx >> 8;
        bf16x8 o;
#pragma unroll
        for (int e = 0; e < 8; ++e)
            o[e] = f2bf(w[(k * CIN + ((lane >> 4) * 8 + e)) * COUT + cb * 16 + (lane & 15)]);
        ((bf16x8*)(ws + WSWZ_OFF))[gidx] = o;
    }
    grid.sync();

    // Phase 1: scatter (grid-stride over n inputs)
    for (int i = gidx; i < n; i += PREP_BLOCKS * 256) {
        int x = pos[i * 3 + 0];
        int y = pos[i * 3 + 1];
        int z = pos[i * 3 + 2];
        int cell = ((x >> 1) * GC + (y >> 1)) * GC + (z >> 1);
        int k = ((x & 1) << 2) | ((y & 1) << 1) | (z & 1);
        tab[cell * 8 + k] = i;
        atomicOr(&occ[cell], 1 << k);
    }
    grid.sync();

    // Phase 2: per-block occupied counts (block owns 512 cells, thread owns 2)
    int2 o2 = ((const int2*)occ)[gidx];
    int c0 = (o2.x != 0), c1 = (o2.y != 0);
    int s = c0 + c1;
    lds[tid] = s;
    __syncthreads();
    for (int off = 128; off > 0; off >>= 1) {
        if (tid < off) lds[tid] += lds[tid + off];
        __syncthreads();
    }
    if (tid == 0) blockSums[bid] = lds[0];
    grid.sync();

    // Phase 3: block 0 scans the 512 block sums -> exclusive, in place
    if (bid == 0) {
        int a = blockSums[2 * tid], b = blockSums[2 * tid + 1];
        lds[tid] = a + b;
        __syncthreads();
        for (int off = 1; off < 256; off <<= 1) {
            int t = (tid >= off) ? lds[tid - off] : 0;
            __syncthreads();
            lds[tid] += t;
            __syncthreads();
        }
        int excl = lds[tid] - (a + b);
        blockSums[2 * tid]     = excl;
        blockSums[2 * tid + 1] = excl + a;
    }
    grid.sync();

    // Phase 4: compact (local scan + global offset), write cellList + out_pos
    lds[tid] = s;
    __syncthreads();
    for (int off = 1; off < 256; off <<= 1) {
        int t = (tid >= off) ? lds[tid - off] : 0;
        __syncthreads();
        lds[tid] += t;
        __syncthreads();
    }
    int rank = blockSums[bid] + lds[tid] - s;
    int cellBase = gidx * 2;
    int oc[2] = {o2.x, o2.y};
#pragma unroll
    for (int c = 0; c < 2; ++c) {
        if (oc[c]) {
            int cell = cellBase + c;
            cellList[rank] = cell | (oc[c] << 18);
            int cx = cell >> 12, cy = (cell >> 6) & 63, cz = cell & 63;
            out_pos[rank * 3 + 0] = cx + 0.25f;
            out_pos[rank * 3 + 1] = cy + 0.25f;
            out_pos[rank * 3 + 2] = cz + 0.25f;
            ++rank;
        }
    }
}

// ---- Kernel 2: MFMA gather-GEMM. One wave per 16 output cells.
// K=256 = 8 taps x 32 cin; A rows = cells; vacant taps redirected to row 0
// (L2-hot) so all 16 feature loads issue in one branch-free clause; their
// contributions are masked at bf16-convert time.
__global__ __launch_bounds__(256) void conv_kernel(
    const float* __restrict__ feat, const short* __restrict__ wswz,
    const int* __restrict__ tab, const int* __restrict__ cellList,
    int M, float* __restrict__ out_feat) {
    const int lane = threadIdx.x & 63;
    const int wv = threadIdx.x >> 6;
    const int base = (blockIdx.x * 4 + wv) * 16;
    if (base >= M) return;
    const int cslot = lane & 15;     // A-frag row  = cell slot
    const int tgrp  = lane >> 4;     // A-frag K-chunk (8 elems) = cin chunk

    int rank = base + cslot;
    if (rank >= M) rank = M - 1;                 // dup last cell; C-write masked
    int e = cellList[rank];
    int cell = e & 0x3FFFF;
    int occ8 = (e >> 18) & 0xFF;

    const int4* tp = (const int4*)(tab + cell * 8);
    int4 t0 = tp[0], t1 = tp[1];
    int rr[8] = {t0.x, t0.y, t0.z, t0.w, t1.x, t1.y, t1.z, t1.w};

    // Phase 1: branch-free gather — vacant taps read row 0 (cache-hot)
    float4 u[8], v[8];
#pragma unroll
    for (int k = 0; k < 8; ++k) {
        int r = ((occ8 >> k) & 1) ? rr[k] : 0;   // v_cndmask, no branch
        const float4* fr = (const float4*)(feat + (size_t)r * CIN + tgrp * 8);
        u[k] = fr[0];
        v[k] = fr[1];
    }

    // Phase 2: masked convert + 32 MFMAs (4 cout-blocks x 8 K-steps)
    const bf16x8* wf = (const bf16x8*)wswz;
    f32x4 acc0 = {0.f, 0.f, 0.f, 0.f}, acc1 = acc0, acc2 = acc0, acc3 = acc0;
#pragma unroll
    for (int k = 0; k < 8; ++k) {
        bf16x8 a = {0, 0, 0, 0, 0, 0, 0, 0};
        if ((occ8 >> k) & 1) {
            a[0] = f2bf(u[k].x); a[1] = f2bf(u[k].y);
            a[2] = f2bf(u[k].z); a[3] = f2bf(u[k].w);
            a[4] = f2bf(v[k].x); a[5] = f2bf(v[k].y);
            a[6] = f2bf(v[k].z); a[7] = f2bf(v[k].w);
        }
        acc0 = __builtin_amdgcn_mfma_f32_16x16x32_bf16(a, wf[(k * 4 + 0) * 64 + lane], acc0, 0, 0, 0);
        acc1 = __builtin_amdgcn_mfma_f32_16x16x32_bf16(a, wf[(k * 4 + 1) * 64 + lane], acc1, 0, 0, 0);
        acc2 = __builtin_amdgcn_mfma_f32_16x16x32_bf16(a, wf[(k * 4 + 2) * 64 + lane], acc2, 0, 0, 0);
        acc3 = __builtin_amdgcn_mfma_f32_16x16x32_bf16(a, wf[(k * 4 + 3) * 64 + lane], acc3, 0, 0, 0);
    }

    // C-write: D row = tgrp*4+i (within tile), col = cslot (within cout-block)
#pragma unroll
    for (int i = 0; i < 4; ++i) {
        int row = base + tgrp * 4 + i;
        if (row < M) {
            float* o = out_feat + (size_t)row * COUT + cslot;
            o[0]  = acc0[i];
            o[16] = acc1[i];
            o[32] = acc2[i];
            o[48] = acc3[i];
        }
    }
}

extern "C" void kernel_launch(void* const* d_in, const int* in_sizes, int n_in,
                              void* d_out, int out_size, void* d_ws, size_t ws_size,
                              hipStream_t stream) {
    const float* feat   = (const float*)d_in[0];
    const int*   pos    = (const int*)d_in[1];
    const float* weight = (const float*)d_in[2];
    int n = in_sizes[1] / 3;
    int M = out_size / 67;   // out_feat M*64 + out_pos M*3

    char* ws = (char*)d_ws;
    int* tab       = (int*)(ws + TAB_OFF);
    int* cellList  = (int*)(ws + CL_OFF);
    short* wswz    = (short*)(ws + WSWZ_OFF);

    float* out_feat = (float*)d_out;
    float* out_pos  = (float*)d_out + (size_t)M * COUT;

    void* args[] = {(void*)&weight, (void*)&pos, (void*)&n, (void*)&ws,
                    (void*)&out_pos};
    hipLaunchCooperativeKernel((void*)prep_kernel, dim3(PREP_BLOCKS), dim3(256),
                               args, 0, stream);
    conv_kernel<<<(M + 63) / 64, 256, 0, stream>>>(feat, wswz, tab, cellList,
                                                   M, out_feat);
}

// Round 9
// 67.547 us; speedup vs baseline: 4.0169x; 4.0169x over previous
//
#include <hip/hip_runtime.h>

#define GFINE 128
#define GC 64
#define NCELLS (GC * GC * GC)   // 262144
#define CIN 32
#define COUT 64

typedef __attribute__((ext_vector_type(8))) short bf16x8;   // 8 bf16 (4 VGPR)
typedef __attribute__((ext_vector_type(4))) float f32x4;    // MFMA acc

// round-to-nearest-even float -> bf16 bits
__device__ __forceinline__ short f2bf(float f) {
    union { float f; unsigned u; } v; v.f = f;
    unsigned r = v.u + 0x7fffu + ((v.u >> 16) & 1u);
    return (short)(r >> 16);
}

// workspace layout
#define OCC_OFF   0u               // [NCELLS] int, 1 MB: bit k = tap k occupied
#define RG_OFF    1048576u         // [NCELLS] int, 1 MB: cell -> (hitBase<<8)|occ8
#define META_OFF  2097152u         // [<=NCELLS] int, rank -> (hitBase<<8)|occ8
#define BS_OFF    3145728u         // [256] int2 block sums (cells, hits)
#define WSWZ_OFF  3149824u         // 32 KB bf16 swizzled weights
#define GFEAT_OFF 4194304u         // [N*32] bf16, 19.2 MB, hit-compacted rows

// ---- Kernel 1: setup — zero occ (1 MB), swizzle weights ----
__global__ __launch_bounds__(256) void setup_kernel(const float* __restrict__ w,
                                                    char* __restrict__ ws) {
    int bid = blockIdx.x, tid = threadIdx.x;
    if (bid < 256) {                       // zero occ: 65536 int4
        ((int4*)(ws + OCC_OFF))[bid * 256 + tid] = make_int4(0, 0, 0, 0);
    } else {                               // weight swizzle: 8 blocks x 256 = 2048
        int t = (bid - 256) * 256 + tid;
        int lane = t & 63, cb = (t >> 6) & 3, k = t >> 8;
        bf16x8 o;
#pragma unroll
        for (int e = 0; e < 8; ++e)
            o[e] = f2bf(w[(k * CIN + ((lane >> 4) * 8 + e)) * COUT + cb * 16 + (lane & 15)]);
        ((bf16x8*)(ws + WSWZ_OFF))[t] = o;
    }
}

// ---- Kernel 2: scatter occupancy bits ----
__global__ __launch_bounds__(256) void scatter1_kernel(const int* __restrict__ pos,
                                                       int n, int* __restrict__ occ) {
    int i = blockIdx.x * blockDim.x + threadIdx.x;
    if (i >= n) return;
    int x = pos[i * 3 + 0];
    int y = pos[i * 3 + 1];
    int z = pos[i * 3 + 2];
    int cell = ((x >> 1) * GC + (y >> 1)) * GC + (z >> 1);
    int k = ((x & 1) << 2) | ((y & 1) << 1) | (z & 1);
    atomicOr(&occ[cell], 1 << k);
}

// ---- Kernel 3: per-1024-cell block counts: occupied cells + total hits ----
__global__ __launch_bounds__(256) void sum_kernel(const int* __restrict__ occ,
                                                  int2* __restrict__ blockSums) {
    __shared__ int lds[256];
    int tid = threadIdx.x, bid = blockIdx.x;
    int4 o = ((const int4*)occ)[bid * 256 + tid];
    int s = (o.x != 0) + (o.y != 0) + (o.z != 0) + (o.w != 0);
    int h = __builtin_popcount(o.x) + __builtin_popcount(o.y) +
            __builtin_popcount(o.z) + __builtin_popcount(o.w);
    lds[tid] = (h << 16) | s;                     // packed: h<=32, s<=4 per thread
    __syncthreads();
    for (int off = 128; off > 0; off >>= 1) {
        if (tid < off) lds[tid] += lds[tid + off];
        __syncthreads();
    }
    if (tid == 0) blockSums[bid] = make_int2(lds[0] & 0xFFFF, lds[0] >> 16);
}

// ---- Kernel 4: dual scan (cells, hits) + compact ----
// Writes: out_pos[rank], meta[rank] = rank_grid[cell] = (hitBase<<8)|occ8.
__global__ __launch_bounds__(256) void compact_kernel(
    const int* __restrict__ occ, const int2* __restrict__ blockSums,
    int* __restrict__ meta, int* __restrict__ rank_grid,
    float* __restrict__ out_pos) {
    __shared__ int lds[256];
    __shared__ unsigned long long ldsb[256];
    int tid = threadIdx.x, bid = blockIdx.x;
    int4 o = ((const int4*)occ)[bid * 256 + tid];
    int oc[4] = {o.x, o.y, o.z, o.w};
    int s = (o.x != 0) + (o.y != 0) + (o.z != 0) + (o.w != 0);
    int h = __builtin_popcount(o.x) + __builtin_popcount(o.y) +
            __builtin_popcount(o.z) + __builtin_popcount(o.w);
    lds[tid] = (h << 16) | s;
    int2 bs = blockSums[tid];
    ldsb[tid] = ((unsigned long long)bs.y << 32) | (unsigned)bs.x;
    __syncthreads();
    for (int off = 1; off < 256; off <<= 1) {
        int t = (tid >= off) ? lds[tid - off] : 0;
        unsigned long long tb = (tid >= off) ? ldsb[tid - off] : 0ull;
        __syncthreads();
        lds[tid] += t;
        ldsb[tid] += tb;
        __syncthreads();
    }
    unsigned long long g = bid ? ldsb[bid - 1] : 0ull;   // exclusive global prefix
    int incl = lds[tid];
    int rank    = (int)(g & 0xFFFFFFFFull) + (incl & 0xFFFF) - s;
    int hitBase = (int)(g >> 32) + (incl >> 16) - h;
    int cellBase = (bid * 256 + tid) * 4;
#pragma unroll
    for (int c = 0; c < 4; ++c) {
        if (oc[c]) {
            int cell = cellBase + c;
            int mv = (hitBase << 8) | oc[c];
            meta[rank] = mv;
            rank_grid[cell] = mv;
            int cx = cell >> 12, cy = (cell >> 6) & 63, cz = cell & 63;
            out_pos[rank * 3 + 0] = cx + 0.25f;
            out_pos[rank * 3 + 1] = cy + 0.25f;
            out_pos[rank * 3 + 2] = cz + 0.25f;
            ++rank;
            hitBase += __builtin_popcount(oc[c]);
        }
    }
}

// ---- Kernel 5: reorder — stream feat rows (sequential read), convert to
// bf16, scatter-write into hit-compacted rank-ordered gfeat ----
__global__ __launch_bounds__(256) void scatter2_kernel(
    const int* __restrict__ pos, const float* __restrict__ feat, int n,
    const int* __restrict__ rank_grid, short* __restrict__ gfeat) {
    int i = blockIdx.x * blockDim.x + threadIdx.x;
    if (i >= n) return;
    int x = pos[i * 3 + 0];
    int y = pos[i * 3 + 1];
    int z = pos[i * 3 + 2];
    int cell = ((x >> 1) * GC + (y >> 1)) * GC + (z >> 1);
    int k = ((x & 1) << 2) | ((y & 1) << 1) | (z & 1);
    int mg = rank_grid[cell];
    int dest = (mg >> 8) + __builtin_popcount(mg & ((1 << k) - 1));
    const float4* fr = (const float4*)(feat + (size_t)i * CIN);
    bf16x8* gp = (bf16x8*)gfeat + dest * 4;
#pragma unroll
    for (int q = 0; q < 4; ++q) {
        float4 a = fr[2 * q], b = fr[2 * q + 1];
        bf16x8 o;
        o[0] = f2bf(a.x); o[1] = f2bf(a.y); o[2] = f2bf(a.z); o[3] = f2bf(a.w);
        o[4] = f2bf(b.x); o[5] = f2bf(b.y); o[6] = f2bf(b.z); o[7] = f2bf(b.w);
        gp[q] = o;
    }
}

// ---- Kernel 6: MFMA conv — fully streaming. One wave per 16 output cells.
// A rows come straight from gfeat (rank-ordered, hit-compacted, bf16);
// vacant taps read row 0 (L1-hot) and are masked at the select.
__global__ __launch_bounds__(256) void conv_kernel(
    const short* __restrict__ gfeat, const short* __restrict__ wswz,
    const int* __restrict__ meta, int M, float* __restrict__ out_feat) {
    const int lane = threadIdx.x & 63;
    const int wv = threadIdx.x >> 6;
    const int base = (blockIdx.x * 4 + wv) * 16;
    if (base >= M) return;
    const int cslot = lane & 15;     // A-frag row  = cell slot
    const int tgrp  = lane >> 4;     // A-frag K-chunk (8 elems) = cin chunk

    int rank = base + cslot;
    if (rank >= M) rank = M - 1;                 // dup last cell; C-write masked
    int mg = meta[rank];
    int hb = mg >> 8;
    int occ8 = mg & 0xFF;

    const bf16x8* gf = (const bf16x8*)gfeat;     // row r chunk q at gf[r*4+q]
    const bf16x8 zero = {0, 0, 0, 0, 0, 0, 0, 0};
    bf16x8 a[8];
#pragma unroll
    for (int k = 0; k < 8; ++k) {
        int bit = (occ8 >> k) & 1;
        int row = hb + __builtin_popcount(occ8 & ((1 << k) - 1));
        row = bit ? row : 0;                     // row 0 always valid, L1-hot
        bf16x8 t = gf[row * 4 + tgrp];
        a[k] = bit ? t : zero;
    }

    const bf16x8* wf = (const bf16x8*)wswz;
    f32x4 acc0 = {0.f, 0.f, 0.f, 0.f}, acc1 = acc0, acc2 = acc0, acc3 = acc0;
#pragma unroll
    for (int k = 0; k < 8; ++k) {
        acc0 = __builtin_amdgcn_mfma_f32_16x16x32_bf16(a[k], wf[(k * 4 + 0) * 64 + lane], acc0, 0, 0, 0);
        acc1 = __builtin_amdgcn_mfma_f32_16x16x32_bf16(a[k], wf[(k * 4 + 1) * 64 + lane], acc1, 0, 0, 0);
        acc2 = __builtin_amdgcn_mfma_f32_16x16x32_bf16(a[k], wf[(k * 4 + 2) * 64 + lane], acc2, 0, 0, 0);
        acc3 = __builtin_amdgcn_mfma_f32_16x16x32_bf16(a[k], wf[(k * 4 + 3) * 64 + lane], acc3, 0, 0, 0);
    }

    // C-write: D row = tgrp*4+i (within tile), col = cslot (within cout-block)
#pragma unroll
    for (int i = 0; i < 4; ++i) {
        int row = base + tgrp * 4 + i;
        if (row < M) {
            float* o = out_feat + (size_t)row * COUT + cslot;
            o[0]  = acc0[i];
            o[16] = acc1[i];
            o[32] = acc2[i];
            o[48] = acc3[i];
        }
    }
}

extern "C" void kernel_launch(void* const* d_in, const int* in_sizes, int n_in,
                              void* d_out, int out_size, void* d_ws, size_t ws_size,
                              hipStream_t stream) {
    const float* feat   = (const float*)d_in[0];
    const int*   pos    = (const int*)d_in[1];
    const float* weight = (const float*)d_in[2];
    int n = in_sizes[1] / 3;
    int M = out_size / 67;   // out_feat M*64 + out_pos M*3

    char* ws = (char*)d_ws;
    int*   occ       = (int*)(ws + OCC_OFF);
    int*   rank_grid = (int*)(ws + RG_OFF);
    int*   meta      = (int*)(ws + META_OFF);
    int2*  blockSums = (int2*)(ws + BS_OFF);
    short* wswz      = (short*)(ws + WSWZ_OFF);
    short* gfeat     = (short*)(ws + GFEAT_OFF);

    float* out_feat = (float*)d_out;
    float* out_pos  = (float*)d_out + (size_t)M * COUT;

    setup_kernel<<<264, 256, 0, stream>>>(weight, ws);
    scatter1_kernel<<<(n + 255) / 256, 256, 0, stream>>>(pos, n, occ);
    sum_kernel<<<256, 256, 0, stream>>>(occ, blockSums);
    compact_kernel<<<256, 256, 0, stream>>>(occ, blockSums, meta, rank_grid, out_pos);
    scatter2_kernel<<<(n + 255) / 256, 256, 0, stream>>>(pos, feat, n, rank_grid, gfeat);
    conv_kernel<<<(M + 63) / 64, 256, 0, stream>>>(gfeat, wswz, meta, M, out_feat);
}